// Round 23
// baseline (176.400 us; speedup 1.0000x reference)
//
#include <hip/hip_runtime.h>
#include <hip/hip_bf16.h>

// MDN NLL, fully fused. N=524288 Dx=128 Dt=64 M=32 K=8.
// R23 = R20 (114.6us best) with the expert decomposition recomposed:
//   wave = (expert kx=wv&7, sample-half sh=wv>>3), FULL-expert fp8 frags
//   (bfrag[2][2][4]=32 regs, R22-validated), ONE rt tile per wave.
//   => per wave: 16 MFMAs (balanced, same as R20) but 4 af ds_read_b64
//   (R20: 8) -- x-LDS reads halve (R22's win) without R22's 2x serial
//   chain (R22's regression: 8 consumer waves x 32 MFMAs vs 8 idle).
//   One llp4 write/wave (R20: 2); LSE sums 4 partials (R20: 8).
// Producers/roles = R20: staging x(tid<512)/t(512-768)/y(768-1024),
// gate bf16 waves 0-1, deferred LSE waves 4-5, single lgkm barrier,
// dbuf llp4/glog. Biases via LDS (R19/R22) to hold VALU-live flat.
// Litmus: WRITE_SIZE >60MB => spill regression => revert R20.

#define NN 524288
#define DX 128
#define DT 64
#define MDIM 32
#define KEXP 8
#define TILE_R 32
#define THREADS 1024
#define GRID_MAIN 512
#define TPB 32                   // 16384 tiles / 512 blocks

typedef __bf16 bf16x8 __attribute__((ext_vector_type(8)));
typedef float f32x4 __attribute__((ext_vector_type(4)));
typedef long long i64;

__device__ __forceinline__ bf16x8 cvt8(const f32x4 a, const f32x4 b) {
  bf16x8 r;
  r[0] = (__bf16)a[0]; r[1] = (__bf16)a[1]; r[2] = (__bf16)a[2]; r[3] = (__bf16)a[3];
  r[4] = (__bf16)b[0]; r[5] = (__bf16)b[1]; r[6] = (__bf16)b[2]; r[7] = (__bf16)b[3];
  return r;
}
// pack 8 f32 -> 8 fp8 e4m3 bytes (elem i = byte i) -- validated R18-R22
__device__ __forceinline__ i64 cvt8f8(const f32x4 a, const f32x4 b) {
  int p0 = __builtin_amdgcn_cvt_pk_fp8_f32(a[0], a[1], 0, 0);
  p0 = __builtin_amdgcn_cvt_pk_fp8_f32(a[2], a[3], p0, 1);
  int p1 = __builtin_amdgcn_cvt_pk_fp8_f32(b[0], b[1], 0, 0);
  p1 = __builtin_amdgcn_cvt_pk_fp8_f32(b[2], b[3], p1, 1);
  return (i64)(((unsigned long long)(unsigned)p1 << 32) | (unsigned)p0);
}

#define MFMA16(a, b, c) __builtin_amdgcn_mfma_f32_16x16x32_bf16(a, b, c, 0, 0, 0)
#define MFMA8(a, b, c)  __builtin_amdgcn_mfma_f32_16x16x32_fp8_fp8(a, b, c, 0, 0, 0)

// LDS-only barrier: global loads stay in flight across it (rule 18 fence).
#define B_LDS() do { \
  asm volatile("s_waitcnt lgkmcnt(0)" ::: "memory"); \
  __builtin_amdgcn_s_barrier(); \
  __builtin_amdgcn_sched_barrier(0); } while (0)

#define HL2PI 0.91893853320467274f

__global__ __launch_bounds__(THREADS, 4) void mdn_main(
    const float* __restrict__ x, const float* __restrict__ t,
    const float* __restrict__ y, const float* __restrict__ Wm,
    const float* __restrict__ bm, const float* __restrict__ Wv,
    const float* __restrict__ bv, const float* __restrict__ Wg,
    const float* __restrict__ bg, float* __restrict__ partials,
    float* __restrict__ out_atomic)
{
  __shared__ __align__(16) unsigned char  xs_l[2][TILE_R * DX];   // fp8 2x4KB
  __shared__ __align__(16) unsigned short ts_l[2][TILE_R * DT];   // bf16 2x4KB
  __shared__ __align__(16) float ys_l[2][TILE_R * MDIM];          // f32 2x4KB
  __shared__ __align__(16) unsigned short wg_lds[2 * 64 * 8];     // 2KB
  __shared__ __align__(16) float bm_s[KEXP * MDIM];               // 1KB
  __shared__ __align__(16) float bv_s[KEXP * MDIM];               // 1KB
  __shared__ __align__(16) float llp4[2][TILE_R * 40];            // 10.2KB
  __shared__ __align__(16) float glog[2][TILE_R * 8];             // 2KB
  __shared__ float red_s[16];

  const int tid = threadIdx.x;
  const int lane = tid & 63;
  const int wv = tid >> 6;        // 0..15
  const int l15 = lane & 15;
  const int lhi = lane >> 4;      // 0..3
  const int kx = wv & 7;          // expert
  const int sh = wv >> 3;         // sample half (rows sh*16 .. +16)

  // ---- staging roles (involution: slot s holds global chunk s^(r&7)) ----
  int st_ldsoff;                  // byte offset within destination buffer
  const float* st_base;
  int st_stride;                  // floats per tile
  if (tid < 512) {                // x: 32 rows x 16 chunks (8B fp8 out)
    const int r = tid >> 4, s = tid & 15, g = s ^ (r & 7);
    st_base = x + (size_t)r * DX + g * 8;
    st_stride = TILE_R * DX;
    st_ldsoff = r * 128 + s * 8;
  } else if (tid < 768) {         // t: 32 rows x 8 chunks (16B bf16 out)
    const int u = tid - 512, r = u >> 3, s = u & 7, g = s ^ (r & 7);
    st_base = t + (size_t)r * DT + g * 8;
    st_stride = TILE_R * DT;
    st_ldsoff = r * 128 + s * 16;
  } else {                        // y: 32 rows x 8 chunks (f32x4 out)
    const int u = tid - 768, r = u >> 3, s = u & 7, g = s ^ (r & 7);
    st_base = y + (size_t)r * MDIM + g * 4;
    st_stride = TILE_R * MDIM;
    st_ldsoff = r * 128 + s * 16;
  }

  f32x4 sa, sb;
  auto issue = [&](int tile) {
    const float* p = st_base + (size_t)tile * st_stride;
    sa = *(const f32x4*)p;
    if (tid < 768) sb = *(const f32x4*)(p + 4);
  };
  auto commit = [&](int buf) {
    if (tid < 512)      *(i64*)((char*)xs_l[buf] + st_ldsoff) = cvt8f8(sa, sb);
    else if (tid < 768) *(bf16x8*)((char*)ts_l[buf] + st_ldsoff) = cvt8(sa, sb);
    else                *(f32x4*)((char*)ys_l[buf] + st_ldsoff) = sa;
  };

  const int first = blockIdx.x * TPB;
  issue(first);    // tile-0 loads in flight under the weight prologue

  // biases -> LDS (VALU-live diet)
  if (tid < KEXP * MDIM) bm_s[tid] = bm[tid];
  else if (tid < 2 * KEXP * MDIM) bv_s[tid - KEXP * MDIM] = bv[tid - KEXP * MDIM];
  f32x4 bgv = {0.f, 0.f, 0.f, 0.f};
  if (wv < 2) bgv = *(const f32x4*)&bg[(lhi & 1) * 4];

  // fp8 W fragments, FULL expert per wave (R22-validated): [ct][hh][kk],
  // 2 regs each = 32 VGPRs. A row = l15 (m-col in half hh), k = lhi*8+i.
  i64 bfrag[2][2][4];
  #pragma unroll
  for (int ct = 0; ct < 2; ++ct) {
    const float* W = (ct ? Wv : Wm) + (size_t)kx * (DX * MDIM);
    #pragma unroll
    for (int hh = 0; hh < 2; ++hh) {
      const int mcol = hh * 16 + l15;
      #pragma unroll
      for (int kk = 0; kk < 4; ++kk) {
        f32x4 wa, wb;
        #pragma unroll
        for (int i = 0; i < 4; ++i) {
          wa[i] = W[(kk * 32 + lhi * 8 + i) * MDIM + mcol];
          wb[i] = W[(kk * 32 + lhi * 8 + 4 + i) * MDIM + mcol];
        }
        bfrag[ct][hh][kk] = cvt8f8(wa, wb);
      }
    }
  }
  // Gate weights -> LDS (one wave; rows >= KEXP zero-padded)
  if (wv == 15) {
    #pragma unroll
    for (int kk = 0; kk < 2; ++kk) {
      bf16x8 tmp;
      #pragma unroll
      for (int i = 0; i < 8; ++i) {
        const int d = kk * 32 + lhi * 8 + i;
        tmp[i] = (__bf16)((l15 < KEXP) ? Wg[d * KEXP + l15] : 0.f);
      }
      *(bf16x8*)((char*)wg_lds + (kk * 64 + lane) * 16) = tmp;
    }
  }

  commit(0);
  B_LDS();        // tile 0 + wg + biases visible

  float loss_acc = 0.f;

  auto do_lse = [&](int pb) {   // waves 4-5; 4-partial sum (R22 layout)
    const int rr = (wv - 4) * 16 + l15;
    const f32x4 lgv = *(const f32x4*)&glog[pb][rr * 8 + (lhi & 1) * 4];
    const int kb = (lhi & 1) * 4;
    f32x4 a4;
    #pragma unroll
    for (int j = 0; j < 4; ++j) {
      const f32x4 pq = *(const f32x4*)&llp4[pb][rr * 40 + (kb + j) * 4];
      a4[j] = lgv[j] - (pq[0] + pq[1] + pq[2] + pq[3]) - 32.0f * HL2PI;
    }
    float mg = fmaxf(fmaxf(lgv[0], lgv[1]), fmaxf(lgv[2], lgv[3]));
    float ma = fmaxf(fmaxf(a4[0], a4[1]), fmaxf(a4[2], a4[3]));
    mg = fmaxf(mg, __shfl_xor(mg, 16));
    ma = fmaxf(ma, __shfl_xor(ma, 16));
    float eg = __expf(lgv[0] - mg) + __expf(lgv[1] - mg)
             + __expf(lgv[2] - mg) + __expf(lgv[3] - mg);
    float ea2 = __expf(a4[0] - ma) + __expf(a4[1] - ma)
              + __expf(a4[2] - ma) + __expf(a4[3] - ma);
    eg += __shfl_xor(eg, 16);
    ea2 += __shfl_xor(ea2, 16);
    if (lhi == 0)
      loss_acc += (mg + __logf(eg)) - (ma + __logf(ea2));
  };

  for (int it = 0; it < TPB; ++it) {
    const int cur = it & 1;
    issue(first + ((it + 1 < TPB) ? it + 1 : it));   // next tile, early

    // ---- deferred LSE for iter it-1 (waves 4-5; overlaps MFMAs) ----
    if (it && (wv == 4 || wv == 5)) do_lse(cur ^ 1);

    // ---- gate MFMA (waves 0-1, bf16; ts[cur] visible since barrier) ----
    if (wv < 2) {
      const int rr = wv * 16 + l15;
      const int r7 = rr & 7;
      f32x4 g = {0.f, 0.f, 0.f, 0.f};
      #pragma unroll
      for (int kk = 0; kk < 2; ++kk) {
        const int s = (kk * 4 + lhi) ^ r7;
        const bf16x8 tf = *(const bf16x8*)((const char*)ts_l[cur] + rr * 128 + s * 16);
        const bf16x8 wf = *(const bf16x8*)((const char*)wg_lds + (kk * 64 + lane) * 16);
        g = MFMA16(wf, tf, g);
      }
      if (lhi < 2) {
        f32x4 lg;
        #pragma unroll
        for (int j = 0; j < 4; ++j) lg[j] = g[j] + bgv[j];
        *(f32x4*)&glog[cur][rr * 8 + lhi * 4] = lg;
      }
    }

    // ---- full-expert fp8 MFMAs, ONE rt tile per wave (balanced) ----
    {
      const unsigned char* xc = xs_l[cur];
      const float* yc = ys_l[cur];
      const int rr = sh * 16 + l15;     // sample (B-col = l15)
      const int r7 = rr & 7;
      f32x4 am0 = *(const f32x4*)&bm_s[kx * MDIM + lhi * 4];
      f32x4 am1 = *(const f32x4*)&bm_s[kx * MDIM + 16 + lhi * 4];
      f32x4 av0 = *(const f32x4*)&bv_s[kx * MDIM + lhi * 4];
      f32x4 av1 = *(const f32x4*)&bv_s[kx * MDIM + 16 + lhi * 4];
      #pragma unroll
      for (int kk = 0; kk < 4; ++kk) {
        const int s = (kk * 4 + lhi) ^ r7;
        const i64 af = *(const i64*)(xc + rr * 128 + s * 8);
        am0 = MFMA8(bfrag[0][0][kk], af, am0);
        am1 = MFMA8(bfrag[0][1][kk], af, am1);
        av0 = MFMA8(bfrag[1][0][kk], af, av0);
        av1 = MFMA8(bfrag[1][1][kk], af, av1);
      }
      // D: col = l15 = sample, row = lhi*4+j = m (hh0) / m+16 (hh1)
      const int s0 = lhi ^ r7, s1 = (4 + lhi) ^ r7;
      const f32x4 y0v = *(const f32x4*)&yc[rr * 32 + s0 * 4];
      const f32x4 y1v = *(const f32x4*)&yc[rr * 32 + s1 * 4];
      float part = 0.f;
      #pragma unroll
      for (int j = 0; j < 4; ++j) {
        const float d0 = y0v[j] - am0[j];
        const float d1 = y1v[j] - am1[j];
        part += d0 * d0 * (0.5f * __expf(-av0[j])) + 0.5f * av0[j];
        part += d1 * d1 * (0.5f * __expf(-av1[j])) + 0.5f * av1[j];
      }
      llp4[cur][rr * 40 + kx * 4 + lhi] = part;   // no shuffles
    }

    commit(cur ^ 1);   // write next tile into the other buffers
    B_LDS();           // the ONE barrier: llp4/glog[cur] + stages visible
  }
  if (wv == 4 || wv == 5) do_lse((TPB - 1) & 1);

  // block reduction of loss
  loss_acc += __shfl_xor(loss_acc, 1);
  loss_acc += __shfl_xor(loss_acc, 2);
  loss_acc += __shfl_xor(loss_acc, 4);
  loss_acc += __shfl_xor(loss_acc, 8);
  loss_acc += __shfl_xor(loss_acc, 16);
  loss_acc += __shfl_xor(loss_acc, 32);
  if (lane == 0) red_s[wv] = loss_acc;
  __syncthreads();
  if (tid == 0) {
    float s = 0.f;
    #pragma unroll
    for (int w = 0; w < 16; ++w) s += red_s[w];
    if (partials) partials[blockIdx.x] = s;
    else atomicAdd(out_atomic, s);
  }
}

__global__ void mdn_reg(const float* __restrict__ Wm, const float* __restrict__ Wv,
                        const float* __restrict__ Wg, float* __restrict__ partials,
                        float* __restrict__ out_atomic)
{
  __shared__ float red[4];
  const int gid = blockIdx.x * 256 + threadIdx.x;
  const int stride = 64 * 256;
  float s = 0.f;
  for (int i = gid; i < DX * MDIM * KEXP; i += stride) { float w = Wm[i]; s += w * w; }
  for (int i = gid; i < DX * MDIM * KEXP; i += stride) { float w = Wv[i]; s += w * w; }
  for (int i = gid; i < DT * KEXP; i += stride)        { float w = Wg[i]; s += w * w; }
  s += __shfl_xor(s, 1);
  s += __shfl_xor(s, 2);
  s += __shfl_xor(s, 4);
  s += __shfl_xor(s, 8);
  s += __shfl_xor(s, 16);
  s += __shfl_xor(s, 32);
  if ((threadIdx.x & 63) == 0) red[threadIdx.x >> 6] = s;
  __syncthreads();
  if (threadIdx.x == 0) {
    float b = red[0] + red[1] + red[2] + red[3];
    if (partials) partials[GRID_MAIN + blockIdx.x] = b;
    else atomicAdd(out_atomic, b);
  }
}

__global__ void mdn_final(const float* __restrict__ partials, float* __restrict__ out)
{
  __shared__ float red[4];
  float s = 0.f;
  for (int i = threadIdx.x; i < GRID_MAIN + 64; i += 256) s += partials[i];
  s += __shfl_xor(s, 1);
  s += __shfl_xor(s, 2);
  s += __shfl_xor(s, 4);
  s += __shfl_xor(s, 8);
  s += __shfl_xor(s, 16);
  s += __shfl_xor(s, 32);
  if ((threadIdx.x & 63) == 0) red[threadIdx.x >> 6] = s;
  __syncthreads();
  if (threadIdx.x == 0) out[0] = red[0] + red[1] + red[2] + red[3];
}

extern "C" void kernel_launch(void* const* d_in, const int* in_sizes, int n_in,
                              void* d_out, int out_size, void* d_ws, size_t ws_size,
                              hipStream_t stream)
{
  const float* x  = (const float*)d_in[0];
  const float* t  = (const float*)d_in[1];
  const float* y  = (const float*)d_in[2];
  const float* Wm = (const float*)d_in[3];
  const float* bm = (const float*)d_in[4];
  const float* Wv = (const float*)d_in[5];
  const float* bv = (const float*)d_in[6];
  const float* Wg = (const float*)d_in[7];
  const float* bg = (const float*)d_in[8];
  float* out = (float*)d_out;

  if (ws_size >= (GRID_MAIN + 64) * sizeof(float)) {
    float* partials = (float*)d_ws;
    mdn_main<<<GRID_MAIN, THREADS, 0, stream>>>(x, t, y, Wm, bm, Wv, bv, Wg, bg,
                                                partials, nullptr);
    mdn_reg<<<64, 256, 0, stream>>>(Wm, Wv, Wg, partials, nullptr);
    mdn_final<<<1, 256, 0, stream>>>(partials, out);
  } else {
    hipMemsetAsync(out, 0, sizeof(float), stream);
    mdn_main<<<GRID_MAIN, THREADS, 0, stream>>>(x, t, y, Wm, bm, Wv, bv, Wg, bg,
                                                nullptr, out);
    mdn_reg<<<64, 256, 0, stream>>>(Wm, Wv, Wg, nullptr, out);
  }
}

// Round 24
// 114.305 us; speedup vs baseline: 1.5432x; 1.5432x over previous
//
#include <hip/hip_runtime.h>
#include <hip/hip_bf16.h>

// MDN NLL, fully fused. N=524288 Dx=128 Dt=64 M=32 K=8.
// R24 = R20 VERBATIM (session best, 114.6us): fp8 experts in the R16
// 16-wave structure. wave = (expert kx=wv&7, col-half hh=wv>>3);
// bfrag[2][4] i64 = 16 regs; xs tile fp8 (af = ds_read_b64); single
// lgkm barrier/iter; deferred LSE waves 4-5; gate bf16 waves 0-1;
// shuffle-free partials llp4; involution-swizzled staging.
// Why revert: R21 (tile 64, +6us), R22 (specialization, +20us),
// R23 (full-expert recomposition, +62us spill) all regressed on
// register-allocation cliffs. R20 is the only zero-loop-spill profile
// (WRITE_SIZE 4MB prologue-only). ~1.5x the 75us HBM floor; all pipes
// <45% -- latency-bound plateau of the monolithic-block structure.

#define NN 524288
#define DX 128
#define DT 64
#define MDIM 32
#define KEXP 8
#define TILE_R 32
#define THREADS 1024
#define GRID_MAIN 512
#define TPB 32                   // 16384 tiles / 512 blocks

typedef __bf16 bf16x8 __attribute__((ext_vector_type(8)));
typedef float f32x4 __attribute__((ext_vector_type(4)));
typedef long long i64;

__device__ __forceinline__ bf16x8 cvt8(const f32x4 a, const f32x4 b) {
  bf16x8 r;
  r[0] = (__bf16)a[0]; r[1] = (__bf16)a[1]; r[2] = (__bf16)a[2]; r[3] = (__bf16)a[3];
  r[4] = (__bf16)b[0]; r[5] = (__bf16)b[1]; r[6] = (__bf16)b[2]; r[7] = (__bf16)b[3];
  return r;
}
// pack 8 f32 -> 8 fp8 e4m3 bytes (elem i = byte i) -- validated R18-R23
__device__ __forceinline__ i64 cvt8f8(const f32x4 a, const f32x4 b) {
  int p0 = __builtin_amdgcn_cvt_pk_fp8_f32(a[0], a[1], 0, 0);
  p0 = __builtin_amdgcn_cvt_pk_fp8_f32(a[2], a[3], p0, 1);
  int p1 = __builtin_amdgcn_cvt_pk_fp8_f32(b[0], b[1], 0, 0);
  p1 = __builtin_amdgcn_cvt_pk_fp8_f32(b[2], b[3], p1, 1);
  return (i64)(((unsigned long long)(unsigned)p1 << 32) | (unsigned)p0);
}

#define MFMA16(a, b, c) __builtin_amdgcn_mfma_f32_16x16x32_bf16(a, b, c, 0, 0, 0)
#define MFMA8(a, b, c)  __builtin_amdgcn_mfma_f32_16x16x32_fp8_fp8(a, b, c, 0, 0, 0)

// LDS-only barrier: global loads stay in flight across it (rule 18 fence).
#define B_LDS() do { \
  asm volatile("s_waitcnt lgkmcnt(0)" ::: "memory"); \
  __builtin_amdgcn_s_barrier(); \
  __builtin_amdgcn_sched_barrier(0); } while (0)

#define HL2PI 0.91893853320467274f

__global__ __launch_bounds__(THREADS, 4) void mdn_main(
    const float* __restrict__ x, const float* __restrict__ t,
    const float* __restrict__ y, const float* __restrict__ Wm,
    const float* __restrict__ bm, const float* __restrict__ Wv,
    const float* __restrict__ bv, const float* __restrict__ Wg,
    const float* __restrict__ bg, float* __restrict__ partials,
    float* __restrict__ out_atomic)
{
  __shared__ __align__(16) unsigned char  xs_l[2][TILE_R * DX];   // fp8 2x4KB
  __shared__ __align__(16) unsigned short ts_l[2][TILE_R * DT];   // bf16 2x4KB
  __shared__ __align__(16) float ys_l[2][TILE_R * MDIM];          // f32 2x4KB
  __shared__ __align__(16) unsigned short wg_lds[2 * 64 * 8];     // 2KB
  __shared__ __align__(16) float llp4[2][TILE_R * 68];            // 17.4KB
  __shared__ __align__(16) float glog[2][TILE_R * 8];             // 2KB
  __shared__ float red_s[16];

  const int tid = threadIdx.x;
  const int lane = tid & 63;
  const int wv = tid >> 6;        // 0..15
  const int l15 = lane & 15;
  const int lhi = lane >> 4;      // 0..3
  const int kx = wv & 7;          // expert
  const int hh = wv >> 3;         // column half (m-cols hh*16 .. +16)

  // ---- staging roles (involution: slot s holds global chunk s^(r&7)) ----
  int st_ldsoff;                  // byte offset within destination buffer
  const float* st_base;
  int st_stride;                  // floats per tile
  if (tid < 512) {                // x: 32 rows x 16 chunks (8B fp8 out)
    const int r = tid >> 4, s = tid & 15, g = s ^ (r & 7);
    st_base = x + (size_t)r * DX + g * 8;
    st_stride = TILE_R * DX;
    st_ldsoff = r * 128 + s * 8;
  } else if (tid < 768) {         // t: 32 rows x 8 chunks (16B bf16 out)
    const int u = tid - 512, r = u >> 3, s = u & 7, g = s ^ (r & 7);
    st_base = t + (size_t)r * DT + g * 8;
    st_stride = TILE_R * DT;
    st_ldsoff = r * 128 + s * 16;
  } else {                        // y: 32 rows x 8 chunks (f32x4 out)
    const int u = tid - 768, r = u >> 3, s = u & 7, g = s ^ (r & 7);
    st_base = y + (size_t)r * MDIM + g * 4;
    st_stride = TILE_R * MDIM;
    st_ldsoff = r * 128 + s * 16;
  }

  f32x4 sa, sb;
  auto issue = [&](int tile) {
    const float* p = st_base + (size_t)tile * st_stride;
    sa = *(const f32x4*)p;
    if (tid < 768) sb = *(const f32x4*)(p + 4);
  };
  auto commit = [&](int buf) {
    if (tid < 512)      *(i64*)((char*)xs_l[buf] + st_ldsoff) = cvt8f8(sa, sb);
    else if (tid < 768) *(bf16x8*)((char*)ts_l[buf] + st_ldsoff) = cvt8(sa, sb);
    else                *(f32x4*)((char*)ys_l[buf] + st_ldsoff) = sa;
  };

  const int first = blockIdx.x * TPB;
  issue(first);    // tile-0 loads in flight under the weight prologue

  // biases once, direct from global: lane's 4 m's = hh*16 + lhi*4 + j
  const f32x4 bmean = *(const f32x4*)&bm[kx * MDIM + hh * 16 + lhi * 4];
  const f32x4 blv   = *(const f32x4*)&bv[kx * MDIM + hh * 16 + lhi * 4];
  f32x4 bgv = {0.f, 0.f, 0.f, 0.f};
  if (wv < 2) bgv = *(const f32x4*)&bg[(lhi & 1) * 4];

  // fp8 W fragments (A-operand, transposed MFMA): ct 0 = mean, 1 = logvar;
  // cols = hh*16 + l15; k = lhi*8 + i.  8 frags x 2 regs = 16 VGPRs.
  i64 bfrag[2][4];
  #pragma unroll
  for (int ct = 0; ct < 2; ++ct) {
    const float* W = (ct ? Wv : Wm) + (size_t)kx * (DX * MDIM);
    const int mcol = hh * 16 + l15;
    #pragma unroll
    for (int kk = 0; kk < 4; ++kk) {
      f32x4 wa, wb;
      #pragma unroll
      for (int i = 0; i < 4; ++i) {
        wa[i] = W[(kk * 32 + lhi * 8 + i) * MDIM + mcol];
        wb[i] = W[(kk * 32 + lhi * 8 + 4 + i) * MDIM + mcol];
      }
      bfrag[ct][kk] = cvt8f8(wa, wb);
    }
  }
  // Gate weights -> LDS (one wave; rows >= KEXP zero-padded)
  if (wv == 15) {
    #pragma unroll
    for (int kk = 0; kk < 2; ++kk) {
      bf16x8 tmp;
      #pragma unroll
      for (int i = 0; i < 8; ++i) {
        const int d = kk * 32 + lhi * 8 + i;
        tmp[i] = (__bf16)((l15 < KEXP) ? Wg[d * KEXP + l15] : 0.f);
      }
      *(bf16x8*)((char*)wg_lds + (kk * 64 + lane) * 16) = tmp;
    }
  }

  commit(0);
  B_LDS();        // tile 0 + wg visible

  float loss_acc = 0.f;

  auto do_lse = [&](int pb) {   // waves 4-5; reads llp4/glog[pb]
    const int rr = (wv - 4) * 16 + l15;
    const f32x4 lgv = *(const f32x4*)&glog[pb][rr * 8 + (lhi & 1) * 4];
    const int kb = (lhi & 1) * 4;
    f32x4 a4;
    #pragma unroll
    for (int j = 0; j < 4; ++j) {
      const f32x4 pA = *(const f32x4*)&llp4[pb][rr * 68 + (kb + j) * 4];
      const f32x4 pB = *(const f32x4*)&llp4[pb][rr * 68 + 32 + (kb + j) * 4];
      const float s8 = pA[0] + pA[1] + pA[2] + pA[3]
                     + pB[0] + pB[1] + pB[2] + pB[3];
      a4[j] = lgv[j] - s8 - 32.0f * HL2PI;
    }
    float mg = fmaxf(fmaxf(lgv[0], lgv[1]), fmaxf(lgv[2], lgv[3]));
    float ma = fmaxf(fmaxf(a4[0], a4[1]), fmaxf(a4[2], a4[3]));
    mg = fmaxf(mg, __shfl_xor(mg, 16));
    ma = fmaxf(ma, __shfl_xor(ma, 16));
    float eg = __expf(lgv[0] - mg) + __expf(lgv[1] - mg)
             + __expf(lgv[2] - mg) + __expf(lgv[3] - mg);
    float ea = __expf(a4[0] - ma) + __expf(a4[1] - ma)
             + __expf(a4[2] - ma) + __expf(a4[3] - ma);
    eg += __shfl_xor(eg, 16);
    ea += __shfl_xor(ea, 16);
    if (lhi == 0)
      loss_acc += (mg + __logf(eg)) - (ma + __logf(ea));
  };

  for (int it = 0; it < TPB; ++it) {
    const int cur = it & 1;
    issue(first + ((it + 1 < TPB) ? it + 1 : it));   // next tile, early

    // ---- deferred LSE for iter it-1 (waves 4-5; overlaps MFMAs) ----
    if (it && (wv == 4 || wv == 5)) do_lse(cur ^ 1);

    // ---- gate MFMA (waves 0-1, bf16; ts[cur] visible since barrier) ----
    if (wv < 2) {
      const int rr = wv * 16 + l15;
      const int r7 = rr & 7;
      f32x4 g = {0.f, 0.f, 0.f, 0.f};
      #pragma unroll
      for (int kk = 0; kk < 2; ++kk) {
        const int s = (kk * 4 + lhi) ^ r7;
        const bf16x8 tf = *(const bf16x8*)((const char*)ts_l[cur] + rr * 128 + s * 16);
        const bf16x8 wf = *(const bf16x8*)((const char*)wg_lds + (kk * 64 + lane) * 16);
        g = MFMA16(wf, tf, g);
      }
      if (lhi < 2) {
        f32x4 lg;
        #pragma unroll
        for (int j = 0; j < 4; ++j) lg[j] = g[j] + bgv[j];
        *(f32x4*)&glog[cur][rr * 8 + lhi * 4] = lg;
      }
    }

    // ---- fp8 expert MFMAs + shuffle-free Gaussian-LL partials ----
    const unsigned char* xc = xs_l[cur];
    const float* yc = ys_l[cur];
    #pragma unroll
    for (int rt = 0; rt < 2; ++rt) {
      const int rr = rt * 16 + l15;     // sample (B-col = l15)
      const int r7 = rr & 7;
      f32x4 acc0 = bmean, acc1 = blv;
      #pragma unroll
      for (int kk = 0; kk < 4; ++kk) {
        const int s = (kk * 4 + lhi) ^ r7;
        const i64 af = *(const i64*)(xc + rr * 128 + s * 8);
        acc0 = MFMA8(bfrag[0][kk], af, acc0);
        acc1 = MFMA8(bfrag[1][kk], af, acc1);
      }
      // D: col = l15 = sample, row = lhi*4+j = m (within half hh)
      const int sy = (hh * 4 + lhi) ^ r7;
      const f32x4 y4 = *(const f32x4*)&yc[rr * 32 + sy * 4];
      float part = 0.f;
      #pragma unroll
      for (int j = 0; j < 4; ++j) {
        const float d = y4[j] - acc0[j];
        part += d * d * (0.5f * __expf(-acc1[j])) + 0.5f * acc1[j];
      }
      llp4[cur][rr * 68 + hh * 32 + kx * 4 + lhi] = part;
    }

    commit(cur ^ 1);   // write next tile into the other buffers
    B_LDS();           // the ONE barrier: llp4/glog[cur] + stages visible
  }
  if (wv == 4 || wv == 5) do_lse((TPB - 1) & 1);

  // block reduction of loss
  loss_acc += __shfl_xor(loss_acc, 1);
  loss_acc += __shfl_xor(loss_acc, 2);
  loss_acc += __shfl_xor(loss_acc, 4);
  loss_acc += __shfl_xor(loss_acc, 8);
  loss_acc += __shfl_xor(loss_acc, 16);
  loss_acc += __shfl_xor(loss_acc, 32);
  if (lane == 0) red_s[wv] = loss_acc;
  __syncthreads();
  if (tid == 0) {
    float s = 0.f;
    #pragma unroll
    for (int w = 0; w < 16; ++w) s += red_s[w];
    if (partials) partials[blockIdx.x] = s;
    else atomicAdd(out_atomic, s);
  }
}

__global__ void mdn_reg(const float* __restrict__ Wm, const float* __restrict__ Wv,
                        const float* __restrict__ Wg, float* __restrict__ partials,
                        float* __restrict__ out_atomic)
{
  __shared__ float red[4];
  const int gid = blockIdx.x * 256 + threadIdx.x;
  const int stride = 64 * 256;
  float s = 0.f;
  for (int i = gid; i < DX * MDIM * KEXP; i += stride) { float w = Wm[i]; s += w * w; }
  for (int i = gid; i < DX * MDIM * KEXP; i += stride) { float w = Wv[i]; s += w * w; }
  for (int i = gid; i < DT * KEXP; i += stride)        { float w = Wg[i]; s += w * w; }
  s += __shfl_xor(s, 1);
  s += __shfl_xor(s, 2);
  s += __shfl_xor(s, 4);
  s += __shfl_xor(s, 8);
  s += __shfl_xor(s, 16);
  s += __shfl_xor(s, 32);
  if ((threadIdx.x & 63) == 0) red[threadIdx.x >> 6] = s;
  __syncthreads();
  if (threadIdx.x == 0) {
    float b = red[0] + red[1] + red[2] + red[3];
    if (partials) partials[GRID_MAIN + blockIdx.x] = b;
    else atomicAdd(out_atomic, b);
  }
}

__global__ void mdn_final(const float* __restrict__ partials, float* __restrict__ out)
{
  __shared__ float red[4];
  float s = 0.f;
  for (int i = threadIdx.x; i < GRID_MAIN + 64; i += 256) s += partials[i];
  s += __shfl_xor(s, 1);
  s += __shfl_xor(s, 2);
  s += __shfl_xor(s, 4);
  s += __shfl_xor(s, 8);
  s += __shfl_xor(s, 16);
  s += __shfl_xor(s, 32);
  if ((threadIdx.x & 63) == 0) red[threadIdx.x >> 6] = s;
  __syncthreads();
  if (threadIdx.x == 0) out[0] = red[0] + red[1] + red[2] + red[3];
}

extern "C" void kernel_launch(void* const* d_in, const int* in_sizes, int n_in,
                              void* d_out, int out_size, void* d_ws, size_t ws_size,
                              hipStream_t stream)
{
  const float* x  = (const float*)d_in[0];
  const float* t  = (const float*)d_in[1];
  const float* y  = (const float*)d_in[2];
  const float* Wm = (const float*)d_in[3];
  const float* bm = (const float*)d_in[4];
  const float* Wv = (const float*)d_in[5];
  const float* bv = (const float*)d_in[6];
  const float* Wg = (const float*)d_in[7];
  const float* bg = (const float*)d_in[8];
  float* out = (float*)d_out;

  if (ws_size >= (GRID_MAIN + 64) * sizeof(float)) {
    float* partials = (float*)d_ws;
    mdn_main<<<GRID_MAIN, THREADS, 0, stream>>>(x, t, y, Wm, bm, Wv, bv, Wg, bg,
                                                partials, nullptr);
    mdn_reg<<<64, 256, 0, stream>>>(Wm, Wv, Wg, partials, nullptr);
    mdn_final<<<1, 256, 0, stream>>>(partials, out);
  } else {
    hipMemsetAsync(out, 0, sizeof(float), stream);
    mdn_main<<<GRID_MAIN, THREADS, 0, stream>>>(x, t, y, Wm, bm, Wv, bv, Wg, bg,
                                                nullptr, out);
    mdn_reg<<<64, 256, 0, stream>>>(Wm, Wv, Wg, nullptr, out);
  }
}

// Round 25
// 108.818 us; speedup vs baseline: 1.6211x; 1.0504x over previous
//
#include <hip/hip_runtime.h>
#include <hip/hip_bf16.h>

// MDN NLL, fully fused. N=524288 Dx=128 Dt=64 M=32 K=8.
// R25 = R20/R24 (reproduced best, 114.3us) with GRID 512->256, TPB 32->64:
//   exactly ONE block per CU (was 2 sequential) -> one prologue (weight
//   fragment build + entry drain) and one epilogue per CU instead of two;
//   no inter-block cold-start. Loop body byte-identical; constants only.
// Structure (locked): fp8 experts, wave = (expert kx=wv&7, half hh=wv>>3),
// bfrag[2][4] i64 = 16 regs, xs fp8 tile (ds_read_b64), single lgkm
// barrier/iter, deferred LSE waves 4-5, gate bf16 waves 0-1, shuffle-free
// partials, involution-swizzled staging. Zero loop spill (WRITE_SIZE 4MB
// prologue-only at 512 blocks; expect ~2MB at 256).

#define NN 524288
#define DX 128
#define DT 64
#define MDIM 32
#define KEXP 8
#define TILE_R 32
#define THREADS 1024
#define GRID_MAIN 256
#define TPB 64                   // 16384 tiles / 256 blocks

typedef __bf16 bf16x8 __attribute__((ext_vector_type(8)));
typedef float f32x4 __attribute__((ext_vector_type(4)));
typedef long long i64;

__device__ __forceinline__ bf16x8 cvt8(const f32x4 a, const f32x4 b) {
  bf16x8 r;
  r[0] = (__bf16)a[0]; r[1] = (__bf16)a[1]; r[2] = (__bf16)a[2]; r[3] = (__bf16)a[3];
  r[4] = (__bf16)b[0]; r[5] = (__bf16)b[1]; r[6] = (__bf16)b[2]; r[7] = (__bf16)b[3];
  return r;
}
// pack 8 f32 -> 8 fp8 e4m3 bytes (elem i = byte i) -- validated R18-R24
__device__ __forceinline__ i64 cvt8f8(const f32x4 a, const f32x4 b) {
  int p0 = __builtin_amdgcn_cvt_pk_fp8_f32(a[0], a[1], 0, 0);
  p0 = __builtin_amdgcn_cvt_pk_fp8_f32(a[2], a[3], p0, 1);
  int p1 = __builtin_amdgcn_cvt_pk_fp8_f32(b[0], b[1], 0, 0);
  p1 = __builtin_amdgcn_cvt_pk_fp8_f32(b[2], b[3], p1, 1);
  return (i64)(((unsigned long long)(unsigned)p1 << 32) | (unsigned)p0);
}

#define MFMA16(a, b, c) __builtin_amdgcn_mfma_f32_16x16x32_bf16(a, b, c, 0, 0, 0)
#define MFMA8(a, b, c)  __builtin_amdgcn_mfma_f32_16x16x32_fp8_fp8(a, b, c, 0, 0, 0)

// LDS-only barrier: global loads stay in flight across it (rule 18 fence).
#define B_LDS() do { \
  asm volatile("s_waitcnt lgkmcnt(0)" ::: "memory"); \
  __builtin_amdgcn_s_barrier(); \
  __builtin_amdgcn_sched_barrier(0); } while (0)

#define HL2PI 0.91893853320467274f

__global__ __launch_bounds__(THREADS, 4) void mdn_main(
    const float* __restrict__ x, const float* __restrict__ t,
    const float* __restrict__ y, const float* __restrict__ Wm,
    const float* __restrict__ bm, const float* __restrict__ Wv,
    const float* __restrict__ bv, const float* __restrict__ Wg,
    const float* __restrict__ bg, float* __restrict__ partials,
    float* __restrict__ out_atomic)
{
  __shared__ __align__(16) unsigned char  xs_l[2][TILE_R * DX];   // fp8 2x4KB
  __shared__ __align__(16) unsigned short ts_l[2][TILE_R * DT];   // bf16 2x4KB
  __shared__ __align__(16) float ys_l[2][TILE_R * MDIM];          // f32 2x4KB
  __shared__ __align__(16) unsigned short wg_lds[2 * 64 * 8];     // 2KB
  __shared__ __align__(16) float llp4[2][TILE_R * 68];            // 17.4KB
  __shared__ __align__(16) float glog[2][TILE_R * 8];             // 2KB
  __shared__ float red_s[16];

  const int tid = threadIdx.x;
  const int lane = tid & 63;
  const int wv = tid >> 6;        // 0..15
  const int l15 = lane & 15;
  const int lhi = lane >> 4;      // 0..3
  const int kx = wv & 7;          // expert
  const int hh = wv >> 3;         // column half (m-cols hh*16 .. +16)

  // ---- staging roles (involution: slot s holds global chunk s^(r&7)) ----
  int st_ldsoff;                  // byte offset within destination buffer
  const float* st_base;
  int st_stride;                  // floats per tile
  if (tid < 512) {                // x: 32 rows x 16 chunks (8B fp8 out)
    const int r = tid >> 4, s = tid & 15, g = s ^ (r & 7);
    st_base = x + (size_t)r * DX + g * 8;
    st_stride = TILE_R * DX;
    st_ldsoff = r * 128 + s * 8;
  } else if (tid < 768) {         // t: 32 rows x 8 chunks (16B bf16 out)
    const int u = tid - 512, r = u >> 3, s = u & 7, g = s ^ (r & 7);
    st_base = t + (size_t)r * DT + g * 8;
    st_stride = TILE_R * DT;
    st_ldsoff = r * 128 + s * 16;
  } else {                        // y: 32 rows x 8 chunks (f32x4 out)
    const int u = tid - 768, r = u >> 3, s = u & 7, g = s ^ (r & 7);
    st_base = y + (size_t)r * MDIM + g * 4;
    st_stride = TILE_R * MDIM;
    st_ldsoff = r * 128 + s * 16;
  }

  f32x4 sa, sb;
  auto issue = [&](int tile) {
    const float* p = st_base + (size_t)tile * st_stride;
    sa = *(const f32x4*)p;
    if (tid < 768) sb = *(const f32x4*)(p + 4);
  };
  auto commit = [&](int buf) {
    if (tid < 512)      *(i64*)((char*)xs_l[buf] + st_ldsoff) = cvt8f8(sa, sb);
    else if (tid < 768) *(bf16x8*)((char*)ts_l[buf] + st_ldsoff) = cvt8(sa, sb);
    else                *(f32x4*)((char*)ys_l[buf] + st_ldsoff) = sa;
  };

  const int first = blockIdx.x * TPB;
  issue(first);    // tile-0 loads in flight under the weight prologue

  // biases once, direct from global: lane's 4 m's = hh*16 + lhi*4 + j
  const f32x4 bmean = *(const f32x4*)&bm[kx * MDIM + hh * 16 + lhi * 4];
  const f32x4 blv   = *(const f32x4*)&bv[kx * MDIM + hh * 16 + lhi * 4];
  f32x4 bgv = {0.f, 0.f, 0.f, 0.f};
  if (wv < 2) bgv = *(const f32x4*)&bg[(lhi & 1) * 4];

  // fp8 W fragments (A-operand, transposed MFMA): ct 0 = mean, 1 = logvar;
  // cols = hh*16 + l15; k = lhi*8 + i.  8 frags x 2 regs = 16 VGPRs.
  i64 bfrag[2][4];
  #pragma unroll
  for (int ct = 0; ct < 2; ++ct) {
    const float* W = (ct ? Wv : Wm) + (size_t)kx * (DX * MDIM);
    const int mcol = hh * 16 + l15;
    #pragma unroll
    for (int kk = 0; kk < 4; ++kk) {
      f32x4 wa, wb;
      #pragma unroll
      for (int i = 0; i < 4; ++i) {
        wa[i] = W[(kk * 32 + lhi * 8 + i) * MDIM + mcol];
        wb[i] = W[(kk * 32 + lhi * 8 + 4 + i) * MDIM + mcol];
      }
      bfrag[ct][kk] = cvt8f8(wa, wb);
    }
  }
  // Gate weights -> LDS (one wave; rows >= KEXP zero-padded)
  if (wv == 15) {
    #pragma unroll
    for (int kk = 0; kk < 2; ++kk) {
      bf16x8 tmp;
      #pragma unroll
      for (int i = 0; i < 8; ++i) {
        const int d = kk * 32 + lhi * 8 + i;
        tmp[i] = (__bf16)((l15 < KEXP) ? Wg[d * KEXP + l15] : 0.f);
      }
      *(bf16x8*)((char*)wg_lds + (kk * 64 + lane) * 16) = tmp;
    }
  }

  commit(0);
  B_LDS();        // tile 0 + wg visible

  float loss_acc = 0.f;

  auto do_lse = [&](int pb) {   // waves 4-5; reads llp4/glog[pb]
    const int rr = (wv - 4) * 16 + l15;
    const f32x4 lgv = *(const f32x4*)&glog[pb][rr * 8 + (lhi & 1) * 4];
    const int kb = (lhi & 1) * 4;
    f32x4 a4;
    #pragma unroll
    for (int j = 0; j < 4; ++j) {
      const f32x4 pA = *(const f32x4*)&llp4[pb][rr * 68 + (kb + j) * 4];
      const f32x4 pB = *(const f32x4*)&llp4[pb][rr * 68 + 32 + (kb + j) * 4];
      const float s8 = pA[0] + pA[1] + pA[2] + pA[3]
                     + pB[0] + pB[1] + pB[2] + pB[3];
      a4[j] = lgv[j] - s8 - 32.0f * HL2PI;
    }
    float mg = fmaxf(fmaxf(lgv[0], lgv[1]), fmaxf(lgv[2], lgv[3]));
    float ma = fmaxf(fmaxf(a4[0], a4[1]), fmaxf(a4[2], a4[3]));
    mg = fmaxf(mg, __shfl_xor(mg, 16));
    ma = fmaxf(ma, __shfl_xor(ma, 16));
    float eg = __expf(lgv[0] - mg) + __expf(lgv[1] - mg)
             + __expf(lgv[2] - mg) + __expf(lgv[3] - mg);
    float ea = __expf(a4[0] - ma) + __expf(a4[1] - ma)
             + __expf(a4[2] - ma) + __expf(a4[3] - ma);
    eg += __shfl_xor(eg, 16);
    ea += __shfl_xor(ea, 16);
    if (lhi == 0)
      loss_acc += (mg + __logf(eg)) - (ma + __logf(ea));
  };

  for (int it = 0; it < TPB; ++it) {
    const int cur = it & 1;
    issue(first + ((it + 1 < TPB) ? it + 1 : it));   // next tile, early

    // ---- deferred LSE for iter it-1 (waves 4-5; overlaps MFMAs) ----
    if (it && (wv == 4 || wv == 5)) do_lse(cur ^ 1);

    // ---- gate MFMA (waves 0-1, bf16; ts[cur] visible since barrier) ----
    if (wv < 2) {
      const int rr = wv * 16 + l15;
      const int r7 = rr & 7;
      f32x4 g = {0.f, 0.f, 0.f, 0.f};
      #pragma unroll
      for (int kk = 0; kk < 2; ++kk) {
        const int s = (kk * 4 + lhi) ^ r7;
        const bf16x8 tf = *(const bf16x8*)((const char*)ts_l[cur] + rr * 128 + s * 16);
        const bf16x8 wf = *(const bf16x8*)((const char*)wg_lds + (kk * 64 + lane) * 16);
        g = MFMA16(wf, tf, g);
      }
      if (lhi < 2) {
        f32x4 lg;
        #pragma unroll
        for (int j = 0; j < 4; ++j) lg[j] = g[j] + bgv[j];
        *(f32x4*)&glog[cur][rr * 8 + lhi * 4] = lg;
      }
    }

    // ---- fp8 expert MFMAs + shuffle-free Gaussian-LL partials ----
    const unsigned char* xc = xs_l[cur];
    const float* yc = ys_l[cur];
    #pragma unroll
    for (int rt = 0; rt < 2; ++rt) {
      const int rr = rt * 16 + l15;     // sample (B-col = l15)
      const int r7 = rr & 7;
      f32x4 acc0 = bmean, acc1 = blv;
      #pragma unroll
      for (int kk = 0; kk < 4; ++kk) {
        const int s = (kk * 4 + lhi) ^ r7;
        const i64 af = *(const i64*)(xc + rr * 128 + s * 8);
        acc0 = MFMA8(bfrag[0][kk], af, acc0);
        acc1 = MFMA8(bfrag[1][kk], af, acc1);
      }
      // D: col = l15 = sample, row = lhi*4+j = m (within half hh)
      const int sy = (hh * 4 + lhi) ^ r7;
      const f32x4 y4 = *(const f32x4*)&yc[rr * 32 + sy * 4];
      float part = 0.f;
      #pragma unroll
      for (int j = 0; j < 4; ++j) {
        const float d = y4[j] - acc0[j];
        part += d * d * (0.5f * __expf(-acc1[j])) + 0.5f * acc1[j];
      }
      llp4[cur][rr * 68 + hh * 32 + kx * 4 + lhi] = part;
    }

    commit(cur ^ 1);   // write next tile into the other buffers
    B_LDS();           // the ONE barrier: llp4/glog[cur] + stages visible
  }
  if (wv == 4 || wv == 5) do_lse((TPB - 1) & 1);

  // block reduction of loss
  loss_acc += __shfl_xor(loss_acc, 1);
  loss_acc += __shfl_xor(loss_acc, 2);
  loss_acc += __shfl_xor(loss_acc, 4);
  loss_acc += __shfl_xor(loss_acc, 8);
  loss_acc += __shfl_xor(loss_acc, 16);
  loss_acc += __shfl_xor(loss_acc, 32);
  if (lane == 0) red_s[wv] = loss_acc;
  __syncthreads();
  if (tid == 0) {
    float s = 0.f;
    #pragma unroll
    for (int w = 0; w < 16; ++w) s += red_s[w];
    if (partials) partials[blockIdx.x] = s;
    else atomicAdd(out_atomic, s);
  }
}

__global__ void mdn_reg(const float* __restrict__ Wm, const float* __restrict__ Wv,
                        const float* __restrict__ Wg, float* __restrict__ partials,
                        float* __restrict__ out_atomic)
{
  __shared__ float red[4];
  const int gid = blockIdx.x * 256 + threadIdx.x;
  const int stride = 64 * 256;
  float s = 0.f;
  for (int i = gid; i < DX * MDIM * KEXP; i += stride) { float w = Wm[i]; s += w * w; }
  for (int i = gid; i < DX * MDIM * KEXP; i += stride) { float w = Wv[i]; s += w * w; }
  for (int i = gid; i < DT * KEXP; i += stride)        { float w = Wg[i]; s += w * w; }
  s += __shfl_xor(s, 1);
  s += __shfl_xor(s, 2);
  s += __shfl_xor(s, 4);
  s += __shfl_xor(s, 8);
  s += __shfl_xor(s, 16);
  s += __shfl_xor(s, 32);
  if ((threadIdx.x & 63) == 0) red[threadIdx.x >> 6] = s;
  __syncthreads();
  if (threadIdx.x == 0) {
    float b = red[0] + red[1] + red[2] + red[3];
    if (partials) partials[GRID_MAIN + blockIdx.x] = b;
    else atomicAdd(out_atomic, b);
  }
}

__global__ void mdn_final(const float* __restrict__ partials, float* __restrict__ out)
{
  __shared__ float red[4];
  float s = 0.f;
  for (int i = threadIdx.x; i < GRID_MAIN + 64; i += 256) s += partials[i];
  s += __shfl_xor(s, 1);
  s += __shfl_xor(s, 2);
  s += __shfl_xor(s, 4);
  s += __shfl_xor(s, 8);
  s += __shfl_xor(s, 16);
  s += __shfl_xor(s, 32);
  if ((threadIdx.x & 63) == 0) red[threadIdx.x >> 6] = s;
  __syncthreads();
  if (threadIdx.x == 0) out[0] = red[0] + red[1] + red[2] + red[3];
}

extern "C" void kernel_launch(void* const* d_in, const int* in_sizes, int n_in,
                              void* d_out, int out_size, void* d_ws, size_t ws_size,
                              hipStream_t stream)
{
  const float* x  = (const float*)d_in[0];
  const float* t  = (const float*)d_in[1];
  const float* y  = (const float*)d_in[2];
  const float* Wm = (const float*)d_in[3];
  const float* bm = (const float*)d_in[4];
  const float* Wv = (const float*)d_in[5];
  const float* bv = (const float*)d_in[6];
  const float* Wg = (const float*)d_in[7];
  const float* bg = (const float*)d_in[8];
  float* out = (float*)d_out;

  if (ws_size >= (GRID_MAIN + 64) * sizeof(float)) {
    float* partials = (float*)d_ws;
    mdn_main<<<GRID_MAIN, THREADS, 0, stream>>>(x, t, y, Wm, bm, Wv, bv, Wg, bg,
                                                partials, nullptr);
    mdn_reg<<<64, 256, 0, stream>>>(Wm, Wv, Wg, partials, nullptr);
    mdn_final<<<1, 256, 0, stream>>>(partials, out);
  } else {
    hipMemsetAsync(out, 0, sizeof(float), stream);
    mdn_main<<<GRID_MAIN, THREADS, 0, stream>>>(x, t, y, Wm, bm, Wv, bv, Wg, bg,
                                                nullptr, out);
    mdn_reg<<<64, 256, 0, stream>>>(Wm, Wv, Wg, nullptr, out);
  }
}

// Round 26
// 107.976 us; speedup vs baseline: 1.6337x; 1.0078x over previous
//
#include <hip/hip_runtime.h>
#include <hip/hip_bf16.h>

// MDN NLL, fully fused. N=524288 Dx=128 Dt=64 M=32 K=8.
// R26 = R25 (108.8us best) + 4-BIT x INVOLUTION (two-line change):
//   x row stride = 128B = exactly 32 banks, so bank-pair = slot mod 16.
//   Old slot = (kk*4+lhi)^(rr&7) spans only 8 values -> 8 lanes/pair
//   (2x the uniform minimum for b64). New: slot = chunk ^ (rr&15)
//   (rr&15 = l15) -> bank-pair = (kk*4+lhi)^l15 hits all 16 values
//   exactly 4x = conflict-free b64 distribution. Staging side mirrors
//   with g = s ^ (r&15) (same involution algebra). y/ts already uniform.
//   Predicted: SQ_LDS_BANK_CONFLICT 6.4M -> <=2M, ~-5..10us.
// Structure (locked, R20/R24/R25): fp8 experts, wave=(kx=wv&7,hh=wv>>3),
// bfrag[2][4] i64=16 regs, single lgkm barrier/iter, deferred LSE waves
// 4-5, gate bf16 waves 0-1, shuffle-free partials, GRID=256 (1 block/CU),
// TPB=64, zero loop spill.

#define NN 524288
#define DX 128
#define DT 64
#define MDIM 32
#define KEXP 8
#define TILE_R 32
#define THREADS 1024
#define GRID_MAIN 256
#define TPB 64                   // 16384 tiles / 256 blocks

typedef __bf16 bf16x8 __attribute__((ext_vector_type(8)));
typedef float f32x4 __attribute__((ext_vector_type(4)));
typedef long long i64;

__device__ __forceinline__ bf16x8 cvt8(const f32x4 a, const f32x4 b) {
  bf16x8 r;
  r[0] = (__bf16)a[0]; r[1] = (__bf16)a[1]; r[2] = (__bf16)a[2]; r[3] = (__bf16)a[3];
  r[4] = (__bf16)b[0]; r[5] = (__bf16)b[1]; r[6] = (__bf16)b[2]; r[7] = (__bf16)b[3];
  return r;
}
// pack 8 f32 -> 8 fp8 e4m3 bytes (elem i = byte i) -- validated R18-R25
__device__ __forceinline__ i64 cvt8f8(const f32x4 a, const f32x4 b) {
  int p0 = __builtin_amdgcn_cvt_pk_fp8_f32(a[0], a[1], 0, 0);
  p0 = __builtin_amdgcn_cvt_pk_fp8_f32(a[2], a[3], p0, 1);
  int p1 = __builtin_amdgcn_cvt_pk_fp8_f32(b[0], b[1], 0, 0);
  p1 = __builtin_amdgcn_cvt_pk_fp8_f32(b[2], b[3], p1, 1);
  return (i64)(((unsigned long long)(unsigned)p1 << 32) | (unsigned)p0);
}

#define MFMA16(a, b, c) __builtin_amdgcn_mfma_f32_16x16x32_bf16(a, b, c, 0, 0, 0)
#define MFMA8(a, b, c)  __builtin_amdgcn_mfma_f32_16x16x32_fp8_fp8(a, b, c, 0, 0, 0)

// LDS-only barrier: global loads stay in flight across it (rule 18 fence).
#define B_LDS() do { \
  asm volatile("s_waitcnt lgkmcnt(0)" ::: "memory"); \
  __builtin_amdgcn_s_barrier(); \
  __builtin_amdgcn_sched_barrier(0); } while (0)

#define HL2PI 0.91893853320467274f

__global__ __launch_bounds__(THREADS, 4) void mdn_main(
    const float* __restrict__ x, const float* __restrict__ t,
    const float* __restrict__ y, const float* __restrict__ Wm,
    const float* __restrict__ bm, const float* __restrict__ Wv,
    const float* __restrict__ bv, const float* __restrict__ Wg,
    const float* __restrict__ bg, float* __restrict__ partials,
    float* __restrict__ out_atomic)
{
  __shared__ __align__(16) unsigned char  xs_l[2][TILE_R * DX];   // fp8 2x4KB
  __shared__ __align__(16) unsigned short ts_l[2][TILE_R * DT];   // bf16 2x4KB
  __shared__ __align__(16) float ys_l[2][TILE_R * MDIM];          // f32 2x4KB
  __shared__ __align__(16) unsigned short wg_lds[2 * 64 * 8];     // 2KB
  __shared__ __align__(16) float llp4[2][TILE_R * 68];            // 17.4KB
  __shared__ __align__(16) float glog[2][TILE_R * 8];             // 2KB
  __shared__ float red_s[16];

  const int tid = threadIdx.x;
  const int lane = tid & 63;
  const int wv = tid >> 6;        // 0..15
  const int l15 = lane & 15;
  const int lhi = lane >> 4;      // 0..3
  const int kx = wv & 7;          // expert
  const int hh = wv >> 3;         // column half (m-cols hh*16 .. +16)

  // ---- staging roles ----
  // x: 4-bit involution (slot s holds global chunk s^(r&15)) -> reader
  //    bank-pairs uniform 4/pair.  t/y: 3-bit involution (8 chunks/row).
  int st_ldsoff;                  // byte offset within destination buffer
  const float* st_base;
  int st_stride;                  // floats per tile
  if (tid < 512) {                // x: 32 rows x 16 chunks (8B fp8 out)
    const int r = tid >> 4, s = tid & 15, g = s ^ (r & 15);
    st_base = x + (size_t)r * DX + g * 8;
    st_stride = TILE_R * DX;
    st_ldsoff = r * 128 + s * 8;
  } else if (tid < 768) {         // t: 32 rows x 8 chunks (16B bf16 out)
    const int u = tid - 512, r = u >> 3, s = u & 7, g = s ^ (r & 7);
    st_base = t + (size_t)r * DT + g * 8;
    st_stride = TILE_R * DT;
    st_ldsoff = r * 128 + s * 16;
  } else {                        // y: 32 rows x 8 chunks (f32x4 out)
    const int u = tid - 768, r = u >> 3, s = u & 7, g = s ^ (r & 7);
    st_base = y + (size_t)r * MDIM + g * 4;
    st_stride = TILE_R * MDIM;
    st_ldsoff = r * 128 + s * 16;
  }

  f32x4 sa, sb;
  auto issue = [&](int tile) {
    const float* p = st_base + (size_t)tile * st_stride;
    sa = *(const f32x4*)p;
    if (tid < 768) sb = *(const f32x4*)(p + 4);
  };
  auto commit = [&](int buf) {
    if (tid < 512)      *(i64*)((char*)xs_l[buf] + st_ldsoff) = cvt8f8(sa, sb);
    else if (tid < 768) *(bf16x8*)((char*)ts_l[buf] + st_ldsoff) = cvt8(sa, sb);
    else                *(f32x4*)((char*)ys_l[buf] + st_ldsoff) = sa;
  };

  const int first = blockIdx.x * TPB;
  issue(first);    // tile-0 loads in flight under the weight prologue

  // biases once, direct from global: lane's 4 m's = hh*16 + lhi*4 + j
  const f32x4 bmean = *(const f32x4*)&bm[kx * MDIM + hh * 16 + lhi * 4];
  const f32x4 blv   = *(const f32x4*)&bv[kx * MDIM + hh * 16 + lhi * 4];
  f32x4 bgv = {0.f, 0.f, 0.f, 0.f};
  if (wv < 2) bgv = *(const f32x4*)&bg[(lhi & 1) * 4];

  // fp8 W fragments (A-operand, transposed MFMA): ct 0 = mean, 1 = logvar;
  // cols = hh*16 + l15; k = lhi*8 + i.  8 frags x 2 regs = 16 VGPRs.
  i64 bfrag[2][4];
  #pragma unroll
  for (int ct = 0; ct < 2; ++ct) {
    const float* W = (ct ? Wv : Wm) + (size_t)kx * (DX * MDIM);
    const int mcol = hh * 16 + l15;
    #pragma unroll
    for (int kk = 0; kk < 4; ++kk) {
      f32x4 wa, wb;
      #pragma unroll
      for (int i = 0; i < 4; ++i) {
        wa[i] = W[(kk * 32 + lhi * 8 + i) * MDIM + mcol];
        wb[i] = W[(kk * 32 + lhi * 8 + 4 + i) * MDIM + mcol];
      }
      bfrag[ct][kk] = cvt8f8(wa, wb);
    }
  }
  // Gate weights -> LDS (one wave; rows >= KEXP zero-padded)
  if (wv == 15) {
    #pragma unroll
    for (int kk = 0; kk < 2; ++kk) {
      bf16x8 tmp;
      #pragma unroll
      for (int i = 0; i < 8; ++i) {
        const int d = kk * 32 + lhi * 8 + i;
        tmp[i] = (__bf16)((l15 < KEXP) ? Wg[d * KEXP + l15] : 0.f);
      }
      *(bf16x8*)((char*)wg_lds + (kk * 64 + lane) * 16) = tmp;
    }
  }

  commit(0);
  B_LDS();        // tile 0 + wg visible

  float loss_acc = 0.f;

  auto do_lse = [&](int pb) {   // waves 4-5; reads llp4/glog[pb]
    const int rr = (wv - 4) * 16 + l15;
    const f32x4 lgv = *(const f32x4*)&glog[pb][rr * 8 + (lhi & 1) * 4];
    const int kb = (lhi & 1) * 4;
    f32x4 a4;
    #pragma unroll
    for (int j = 0; j < 4; ++j) {
      const f32x4 pA = *(const f32x4*)&llp4[pb][rr * 68 + (kb + j) * 4];
      const f32x4 pB = *(const f32x4*)&llp4[pb][rr * 68 + 32 + (kb + j) * 4];
      const float s8 = pA[0] + pA[1] + pA[2] + pA[3]
                     + pB[0] + pB[1] + pB[2] + pB[3];
      a4[j] = lgv[j] - s8 - 32.0f * HL2PI;
    }
    float mg = fmaxf(fmaxf(lgv[0], lgv[1]), fmaxf(lgv[2], lgv[3]));
    float ma = fmaxf(fmaxf(a4[0], a4[1]), fmaxf(a4[2], a4[3]));
    mg = fmaxf(mg, __shfl_xor(mg, 16));
    ma = fmaxf(ma, __shfl_xor(ma, 16));
    float eg = __expf(lgv[0] - mg) + __expf(lgv[1] - mg)
             + __expf(lgv[2] - mg) + __expf(lgv[3] - mg);
    float ea = __expf(a4[0] - ma) + __expf(a4[1] - ma)
             + __expf(a4[2] - ma) + __expf(a4[3] - ma);
    eg += __shfl_xor(eg, 16);
    ea += __shfl_xor(ea, 16);
    if (lhi == 0)
      loss_acc += (mg + __logf(eg)) - (ma + __logf(ea));
  };

  for (int it = 0; it < TPB; ++it) {
    const int cur = it & 1;
    issue(first + ((it + 1 < TPB) ? it + 1 : it));   // next tile, early

    // ---- deferred LSE for iter it-1 (waves 4-5; overlaps MFMAs) ----
    if (it && (wv == 4 || wv == 5)) do_lse(cur ^ 1);

    // ---- gate MFMA (waves 0-1, bf16; ts[cur] visible since barrier) ----
    if (wv < 2) {
      const int rr = wv * 16 + l15;
      const int r7 = rr & 7;
      f32x4 g = {0.f, 0.f, 0.f, 0.f};
      #pragma unroll
      for (int kk = 0; kk < 2; ++kk) {
        const int s = (kk * 4 + lhi) ^ r7;
        const bf16x8 tf = *(const bf16x8*)((const char*)ts_l[cur] + rr * 128 + s * 16);
        const bf16x8 wf = *(const bf16x8*)((const char*)wg_lds + (kk * 64 + lane) * 16);
        g = MFMA16(wf, tf, g);
      }
      if (lhi < 2) {
        f32x4 lg;
        #pragma unroll
        for (int j = 0; j < 4; ++j) lg[j] = g[j] + bgv[j];
        *(f32x4*)&glog[cur][rr * 8 + lhi * 4] = lg;
      }
    }

    // ---- fp8 expert MFMAs + shuffle-free Gaussian-LL partials ----
    const unsigned char* xc = xs_l[cur];
    const float* yc = ys_l[cur];
    #pragma unroll
    for (int rt = 0; rt < 2; ++rt) {
      const int rr = rt * 16 + l15;     // sample (B-col = l15)
      const int r7 = rr & 7;
      f32x4 acc0 = bmean, acc1 = blv;
      #pragma unroll
      for (int kk = 0; kk < 4; ++kk) {
        // 4-bit involution: slot = chunk ^ (rr&15); rr&15 == l15
        const int s = (kk * 4 + lhi) ^ l15;
        const i64 af = *(const i64*)(xc + rr * 128 + s * 8);
        acc0 = MFMA8(bfrag[0][kk], af, acc0);
        acc1 = MFMA8(bfrag[1][kk], af, acc1);
      }
      // D: col = l15 = sample, row = lhi*4+j = m (within half hh)
      const int sy = (hh * 4 + lhi) ^ r7;
      const f32x4 y4 = *(const f32x4*)&yc[rr * 32 + sy * 4];
      float part = 0.f;
      #pragma unroll
      for (int j = 0; j < 4; ++j) {
        const float d = y4[j] - acc0[j];
        part += d * d * (0.5f * __expf(-acc1[j])) + 0.5f * acc1[j];
      }
      llp4[cur][rr * 68 + hh * 32 + kx * 4 + lhi] = part;
    }

    commit(cur ^ 1);   // write next tile into the other buffers
    B_LDS();           // the ONE barrier: llp4/glog[cur] + stages visible
  }
  if (wv == 4 || wv == 5) do_lse((TPB - 1) & 1);

  // block reduction of loss
  loss_acc += __shfl_xor(loss_acc, 1);
  loss_acc += __shfl_xor(loss_acc, 2);
  loss_acc += __shfl_xor(loss_acc, 4);
  loss_acc += __shfl_xor(loss_acc, 8);
  loss_acc += __shfl_xor(loss_acc, 16);
  loss_acc += __shfl_xor(loss_acc, 32);
  if (lane == 0) red_s[wv] = loss_acc;
  __syncthreads();
  if (tid == 0) {
    float s = 0.f;
    #pragma unroll
    for (int w = 0; w < 16; ++w) s += red_s[w];
    if (partials) partials[blockIdx.x] = s;
    else atomicAdd(out_atomic, s);
  }
}

__global__ void mdn_reg(const float* __restrict__ Wm, const float* __restrict__ Wv,
                        const float* __restrict__ Wg, float* __restrict__ partials,
                        float* __restrict__ out_atomic)
{
  __shared__ float red[4];
  const int gid = blockIdx.x * 256 + threadIdx.x;
  const int stride = 64 * 256;
  float s = 0.f;
  for (int i = gid; i < DX * MDIM * KEXP; i += stride) { float w = Wm[i]; s += w * w; }
  for (int i = gid; i < DX * MDIM * KEXP; i += stride) { float w = Wv[i]; s += w * w; }
  for (int i = gid; i < DT * KEXP; i += stride)        { float w = Wg[i]; s += w * w; }
  s += __shfl_xor(s, 1);
  s += __shfl_xor(s, 2);
  s += __shfl_xor(s, 4);
  s += __shfl_xor(s, 8);
  s += __shfl_xor(s, 16);
  s += __shfl_xor(s, 32);
  if ((threadIdx.x & 63) == 0) red[threadIdx.x >> 6] = s;
  __syncthreads();
  if (threadIdx.x == 0) {
    float b = red[0] + red[1] + red[2] + red[3];
    if (partials) partials[GRID_MAIN + blockIdx.x] = b;
    else atomicAdd(out_atomic, b);
  }
}

__global__ void mdn_final(const float* __restrict__ partials, float* __restrict__ out)
{
  __shared__ float red[4];
  float s = 0.f;
  for (int i = threadIdx.x; i < GRID_MAIN + 64; i += 256) s += partials[i];
  s += __shfl_xor(s, 1);
  s += __shfl_xor(s, 2);
  s += __shfl_xor(s, 4);
  s += __shfl_xor(s, 8);
  s += __shfl_xor(s, 16);
  s += __shfl_xor(s, 32);
  if ((threadIdx.x & 63) == 0) red[threadIdx.x >> 6] = s;
  __syncthreads();
  if (threadIdx.x == 0) out[0] = red[0] + red[1] + red[2] + red[3];
}

extern "C" void kernel_launch(void* const* d_in, const int* in_sizes, int n_in,
                              void* d_out, int out_size, void* d_ws, size_t ws_size,
                              hipStream_t stream)
{
  const float* x  = (const float*)d_in[0];
  const float* t  = (const float*)d_in[1];
  const float* y  = (const float*)d_in[2];
  const float* Wm = (const float*)d_in[3];
  const float* bm = (const float*)d_in[4];
  const float* Wv = (const float*)d_in[5];
  const float* bv = (const float*)d_in[6];
  const float* Wg = (const float*)d_in[7];
  const float* bg = (const float*)d_in[8];
  float* out = (float*)d_out;

  if (ws_size >= (GRID_MAIN + 64) * sizeof(float)) {
    float* partials = (float*)d_ws;
    mdn_main<<<GRID_MAIN, THREADS, 0, stream>>>(x, t, y, Wm, bm, Wv, bv, Wg, bg,
                                                partials, nullptr);
    mdn_reg<<<64, 256, 0, stream>>>(Wm, Wv, Wg, partials, nullptr);
    mdn_final<<<1, 256, 0, stream>>>(partials, out);
  } else {
    hipMemsetAsync(out, 0, sizeof(float), stream);
    mdn_main<<<GRID_MAIN, THREADS, 0, stream>>>(x, t, y, Wm, bm, Wv, bv, Wg, bg,
                                                nullptr, out);
    mdn_reg<<<64, 256, 0, stream>>>(Wm, Wv, Wg, nullptr, out);
  }
}